// Round 8
// baseline (15938.379 us; speedup 1.0000x reference)
//
#include <hip/hip_runtime.h>
#include <math.h>

// ---------------------------------------------------------------------------
// 2-layer tanh RNN scan, B=128, T=1024, H=768.  Persistent kernel, 256 WGs.
// Round-8: keep r7's PROVEN agent-scope coherence recipe exactly
// (st_ag = sc0 sc1 write-through store; ld_ag = coherent u32 load;
//  one agent acquire fence after the step's single true-dependency wait,
//  then plain cached bulk loads).  Structural changes only:
//   * L2-role split: P1 WGs compute S1(t)=h2(t-1)@W_hh2^T (partial, fp32 to
//     ws) in parallel; P3 WGs do h1(t)@W_ih2^T + S1 -> h2(t), out-partials.
//     Every WG's loop now has exactly ONE true wait (was 2 for L2).
//   * Anti-dep gates via cached flag values off the critical path:
//     h1 4-slot, P 4-slot; out-reduce moved after L1's arrival flag and
//     reads P + flags via ld_ag (no fence needed for those).
//   * Wave-independent flag polling (no syncthreads in waits).
// Roles per group (32 WGs, group = 16 batch rows):
//   lrank 0..7  L1 : 96 cols of W_hh1;  8..19 P3 : 64 cols of W_ih2;
//   lrank 20..31 P1: 64 cols of W_hh2.
// Numerics: bf16 (hi,lo) pairs, 3-product MFMA, fp32 accumulate (proven).
// ---------------------------------------------------------------------------

typedef short s16x8 __attribute__((ext_vector_type(8)));
typedef float fx4   __attribute__((ext_vector_type(4)));

#define NWG    256
#define T_LEN  1024
#define H      768
#define GROUPS 8
#define GROWS  16

// per-group ws layout (bytes)
#define GRP_BASE   8192
#define G_FL1 0               // u32[8]
#define G_FH2 128             // u32[12]
#define G_FS1 256             // u32[12]
#define G_PB  512             // float[4][16][2][12]
#define G_S1  8192            // float[2][16][768]
#define G_H1  106496          // 4 slots x {hi,lo} x 24576B
#define G_H2  303104          // 2 slots x {hi,lo} x 24576B
#define GRP_STRIDE 401408
#define HB_SZ 24576
#define WS_TOTAL (GRP_BASE + GROUPS * GRP_STRIDE)

__device__ __forceinline__ unsigned short f2bf(float x) {
    unsigned u = __float_as_uint(x);
    unsigned r = (u + 0x7FFFu + ((u >> 16) & 1u)) >> 16;   // RNE
    return (unsigned short)r;
}
__device__ __forceinline__ float bf2f(unsigned short b) {
    return __uint_as_float(((unsigned)b) << 16);
}
__device__ __forceinline__ fx4 mfma16(s16x8 a, s16x8 b, fx4 c) {
    return __builtin_amdgcn_mfma_f32_16x16x32_bf16(a, b, c, 0, 0, 0);
}

// ---- proven agent-scope primitives (r2/r3/r7) ------------------------------
__device__ __forceinline__ void st_ag(unsigned* p, unsigned v) {
    __hip_atomic_store(p, v, __ATOMIC_RELAXED, __HIP_MEMORY_SCOPE_AGENT);
}
__device__ __forceinline__ unsigned ld_ag(const unsigned* p) {
    return __hip_atomic_load(p, __ATOMIC_RELAXED, __HIP_MEMORY_SCOPE_AGENT);
}
__device__ __forceinline__ void acq_ag() {
    __builtin_amdgcn_fence(__ATOMIC_ACQUIRE, "agent");
}

__device__ __forceinline__ void load_wfrag(const float* __restrict__ W,
                                           int col, int kk, s16x8& hi, s16x8& lo) {
    const float* p = W + (long)col * H + kk;
#pragma unroll
    for (int j = 0; j < 8; j++) {
        float w = p[j];
        unsigned short h = f2bf(w);
        float r = w - bf2f(h);
        hi[j] = (short)h;
        lo[j] = (short)f2bf(r);
    }
}

__device__ __forceinline__ void ld6(const unsigned short* p, s16x8 (&d)[6]) {
#pragma unroll
    for (int ks = 0; ks < 6; ks++)
        d[ks] = *reinterpret_cast<const s16x8*>(p + ks * 32);
}

__device__ __forceinline__ unsigned wave_min(unsigned v) {
#pragma unroll
    for (int o = 32; o; o >>= 1) {
        unsigned u = (unsigned)__shfl_xor((int)v, o);
        v = v < u ? v : u;
    }
    return v;
}

// Wave-independent: every thread polls (lane i -> flag min(i,n-1)); returns
// the observed min (wave-uniform).  NO fence, NO syncthreads here.
__device__ __forceinline__ unsigned wait_flags(const unsigned* f, int n, unsigned T) {
    int l = (int)(threadIdx.x & 63); if (l >= n) l = n - 1;
    unsigned m;
    long spin = 0;
    for (;;) {
        m = wave_min(ld_ag(f + l));
        if (m >= T) break;
        __builtin_amdgcn_s_sleep(1);
        if (++spin > (1L << 20)) break;   // failsafe
    }
    return m;
}

#define DRAIN() do { asm volatile("s_waitcnt vmcnt(0)" ::: "memory"); __syncthreads(); } while (0)

__global__ __launch_bounds__(256, 1) void rnn_persist(
    const float* __restrict__ x,
    const float* __restrict__ Wih1, const float* __restrict__ Whh1,
    const float* __restrict__ bih1, const float* __restrict__ bhh1,
    const float* __restrict__ Wih2, const float* __restrict__ Whh2,
    const float* __restrict__ bih2, const float* __restrict__ bhh2,
    const float* __restrict__ Wlin, const float* __restrict__ blin,
    float* __restrict__ out, unsigned char* __restrict__ ws)
{
    const int wg = blockIdx.x;
    const int tid = threadIdx.x;
    const int lane = tid & 63;
    const int w = tid >> 6;          // wave 0..3, K range [w*192, +192)
    const int l15 = lane & 15;
    const int lk8 = (lane >> 4) * 8;

    const int group = wg >> 5;       // 0..7
    const int lrank = wg & 31;       // 0..31

    __shared__ float red[4][16][97];

    unsigned char* gb = ws + GRP_BASE + (size_t)group * GRP_STRIDE;
    unsigned* fL1 = (unsigned*)(gb + G_FL1);
    unsigned* fH2 = (unsigned*)(gb + G_FH2);
    unsigned* fS1 = (unsigned*)(gb + G_FS1);
    float*    Pb  = (float*)(gb + G_PB);       // [4][16][2][12]
    float*    S1  = (float*)(gb + G_S1);       // [2][16][768]

    const int kb0 = w * 192;

    if (lrank < 8) {
        // ========================= L1 role ==================================
        const int c = lrank;
        const int col0 = c * 96;

        s16x8 whi[6][6], wlo[6][6];
#pragma unroll
        for (int ks = 0; ks < 6; ks++)
#pragma unroll
            for (int nt = 0; nt < 6; nt++)
                load_wfrag(Whh1, col0 + nt * 16 + l15, kb0 + ks * 32 + lk8,
                           whi[ks][nt], wlo[ks][nt]);

        const int er = tid >> 4;                // row 0..15
        const int ec0 = (tid & 15) * 6;         // 6 consecutive cols
        const int b = group * GROWS + er;
        float bs[6], wi0[6], wi1[6];
#pragma unroll
        for (int j = 0; j < 6; j++) {
            int cg = col0 + ec0 + j;
            bs[j] = bih1[cg] + bhh1[cg];
            wi0[j] = Wih1[cg * 2 + 0];
            wi1[j] = Wih1[cg * 2 + 1];
        }
        const int ov = tid >> 5;                // 0..3 (tid<128)
        const int oj = tid & 31;
        const int orow = 2 * c + (ov >> 1);
        const int ooo = ov & 1;
        const float blv = blin[ooo];

        unsigned fH2c = 0;

        for (int t = 0; t < T_LEN; t++) {
            const int rs = (t + 3) & 3;         // h1(t-1) slot
            const int wsl = t & 3;              // h1(t) slot
            float x0 = x[b * 2048 + t];
            float x1 = x[b * 2048 + 1024 + t];

            if (t) { wait_flags(fL1, 8, (unsigned)t); acq_ag(); }

            const unsigned short* Hh = (const unsigned short*)(gb + G_H1 + rs * 2 * HB_SZ);
            const unsigned short* Hl = (const unsigned short*)(gb + G_H1 + rs * 2 * HB_SZ + HB_SZ);
            s16x8 ah[6], al[6];
            ld6(Hh + l15 * H + kb0 + lk8, ah);
            ld6(Hl + l15 * H + kb0 + lk8, al);

            fx4 acc[6];
#pragma unroll
            for (int nt = 0; nt < 6; nt++) acc[nt] = fx4{0.f, 0.f, 0.f, 0.f};
#pragma unroll
            for (int ks = 0; ks < 6; ks++)
#pragma unroll
                for (int nt = 0; nt < 6; nt++) {
                    acc[nt] = mfma16(ah[ks], whi[ks][nt], acc[nt]);
                    acc[nt] = mfma16(ah[ks], wlo[ks][nt], acc[nt]);
                    acc[nt] = mfma16(al[ks], whi[ks][nt], acc[nt]);
                }

#pragma unroll
            for (int nt = 0; nt < 6; nt++)
#pragma unroll
                for (int i = 0; i < 4; i++)
                    red[w][(lane >> 4) * 4 + i][nt * 16 + l15] = acc[nt][i];
            __syncthreads();

            unsigned hw[3], lw[3];
#pragma unroll
            for (int jj = 0; jj < 3; jj++) {
                unsigned hp = 0, lp = 0;
#pragma unroll
                for (int k = 0; k < 2; k++) {
                    int j = jj * 2 + k;
                    int cc = ec0 + j;
                    float v = red[0][er][cc] + red[1][er][cc] + red[2][er][cc] + red[3][er][cc];
                    v += x0 * wi0[j] + x1 * wi1[j] + bs[j];
                    v = tanhf(v);
                    unsigned short hb = f2bf(v);
                    unsigned short lb = f2bf(v - bf2f(hb));
                    hp |= ((unsigned)hb) << (16 * k);
                    lp |= ((unsigned)lb) << (16 * k);
                }
                hw[jj] = hp; lw[jj] = lp;
            }

            // Anti-dep gate for slot overwrite (h1(t-4)); cached, ~never polls.
            if (t >= 4 && fH2c < (unsigned)(t - 3))
                fH2c = wait_flags(fH2, 12, (unsigned)(t - 3));   // no fence: write-only gate

            unsigned* Dh = (unsigned*)(gb + G_H1 + wsl * 2 * HB_SZ) + ((long)er * H + col0 + ec0) / 2;
            unsigned* Dl = (unsigned*)(gb + G_H1 + wsl * 2 * HB_SZ + HB_SZ) + ((long)er * H + col0 + ec0) / 2;
            st_ag(Dh + 0, hw[0]); st_ag(Dh + 1, hw[1]); st_ag(Dh + 2, hw[2]);
            st_ag(Dl + 0, lw[0]); st_ag(Dl + 1, lw[1]); st_ag(Dl + 2, lw[2]);

            DRAIN();
            if (tid == 0) st_ag(fL1 + c, (unsigned)(t + 1));

            // Off-path: out(t-2) from P slot (t-2)&3, via coherent ld_ag.
            if (t >= 2) {
                fH2c = wait_flags(fH2, 12, (unsigned)(t - 1));
                if (tid < 128) {
                    float p = 0.f;
                    if (oj < 12)
                        p = __uint_as_float(ld_ag((const unsigned*)
                            (Pb + ((((t - 2) & 3) * 16 + orow) * 2 + ooo) * 12 + oj)));
#pragma unroll
                    for (int o = 16; o; o >>= 1) p += __shfl_down(p, o, 32);
                    if (oj == 0) out[(group * GROWS + orow) * 2048 + ooo * 1024 + (t - 2)] = p + blv;
                }
            }
        }

        // tail: P(T-2), P(T-1)
        wait_flags(fH2, 12, (unsigned)T_LEN);
        if (tid < 128) {
#pragma unroll
            for (int par = 0; par < 2; par++) {
                int tt = T_LEN - 2 + par;
                float p = 0.f;
                if (oj < 12)
                    p = __uint_as_float(ld_ag((const unsigned*)
                        (Pb + (((tt & 3) * 16 + orow) * 2 + ooo) * 12 + oj)));
#pragma unroll
                for (int o = 16; o; o >>= 1) p += __shfl_down(p, o, 32);
                if (oj == 0) out[(group * GROWS + orow) * 2048 + ooo * 1024 + tt] = p + blv;
            }
        }
    } else if (lrank < 20) {
        // ========================= P3 role ==================================
        const int c3 = lrank - 8;
        const int col0 = c3 * 64;

        s16x8 ihi[4][6], ilo[4][6];      // W_ih2 fragments
#pragma unroll
        for (int nt = 0; nt < 4; nt++)
#pragma unroll
            for (int ks = 0; ks < 6; ks++)
                load_wfrag(Wih2, col0 + nt * 16 + l15, kb0 + ks * 32 + lk8,
                           ihi[nt][ks], ilo[nt][ks]);

        const int er = tid >> 4;             // 0..15
        const int ec0 = (tid & 15) * 4;      // 4 consecutive cols
        float bs3[4];
#pragma unroll
        for (int j = 0; j < 4; j++)
            bs3[j] = bih2[col0 + ec0 + j] + bhh2[col0 + ec0 + j];

        const int ro = tid >> 1, oo = tid & 1;   // tid<32: out-partial dot
        float wl[64];
        if (tid < 32) {
#pragma unroll
            for (int cc = 0; cc < 64; cc++) wl[cc] = Wlin[oo * H + col0 + cc];
        }

        for (int t = 0; t < T_LEN; t++) {
            // S1(t) ready (also covers h2-slot anti-dep); then the true wait.
            wait_flags(fS1, 12, (unsigned)(t + 1));      // no fence yet
            wait_flags(fL1, 8, (unsigned)(t + 1));
            acq_ag();                                    // covers S1 + h1 loads

            const int hs = t & 3;
            const unsigned short* Hh = (const unsigned short*)(gb + G_H1 + hs * 2 * HB_SZ);
            const unsigned short* Hl = (const unsigned short*)(gb + G_H1 + hs * 2 * HB_SZ + HB_SZ);
            s16x8 ah[6], al[6];
            ld6(Hh + l15 * H + kb0 + lk8, ah);
            ld6(Hl + l15 * H + kb0 + lk8, al);

            fx4 a2[4];
#pragma unroll
            for (int nt = 0; nt < 4; nt++) a2[nt] = fx4{0.f, 0.f, 0.f, 0.f};
#pragma unroll
            for (int ks = 0; ks < 6; ks++)
#pragma unroll
                for (int nt = 0; nt < 4; nt++) {
                    a2[nt] = mfma16(ah[ks], ihi[nt][ks], a2[nt]);
                    a2[nt] = mfma16(ah[ks], ilo[nt][ks], a2[nt]);
                    a2[nt] = mfma16(al[ks], ihi[nt][ks], a2[nt]);
                }

#pragma unroll
            for (int nt = 0; nt < 4; nt++)
#pragma unroll
                for (int i = 0; i < 4; i++)
                    red[w][(lane >> 4) * 4 + i][nt * 16 + l15] = a2[nt][i];
            __syncthreads();

            const float* S1p = S1 + (t & 1) * (16 * H) + (long)er * H + col0 + ec0;
            float vv[4];
            unsigned hp[2], lp[2];
#pragma unroll
            for (int jj = 0; jj < 2; jj++) {
                unsigned hq = 0, lq = 0;
#pragma unroll
                for (int k = 0; k < 2; k++) {
                    int j = jj * 2 + k;
                    int cc = ec0 + j;
                    float v = red[0][er][cc] + red[1][er][cc] + red[2][er][cc] + red[3][er][cc];
                    v += S1p[j] + bs3[j];
                    v = tanhf(v);
                    vv[j] = v;
                    unsigned short hb = f2bf(v);
                    unsigned short lb = f2bf(v - bf2f(hb));
                    hq |= ((unsigned)hb) << (16 * k);
                    lq |= ((unsigned)lb) << (16 * k);
                }
                hp[jj] = hq; lp[jj] = lq;
            }
            unsigned* Dh = (unsigned*)(gb + G_H2 + (t & 1) * 2 * HB_SZ) + ((long)er * H + col0 + ec0) / 2;
            unsigned* Dl = (unsigned*)(gb + G_H2 + (t & 1) * 2 * HB_SZ + HB_SZ) + ((long)er * H + col0 + ec0) / 2;
            st_ag(Dh + 0, hp[0]); st_ag(Dh + 1, hp[1]);
            st_ag(Dl + 0, lp[0]); st_ag(Dl + 1, lp[1]);

            // element-owned overwrite of red[0] for the out-dot
#pragma unroll
            for (int j = 0; j < 4; j++) red[0][er][ec0 + j] = vv[j];
            __syncthreads();

            if (tid < 32) {
                float s = 0.f;
#pragma unroll
                for (int cc = 0; cc < 64; cc++) s += red[0][ro][cc] * wl[cc];
                st_ag((unsigned*)&Pb[(((t & 3) * 16 + ro) * 2 + oo) * 12 + c3],
                      __float_as_uint(s));
            }

            DRAIN();
            if (tid == 0) st_ag(fH2 + c3, (unsigned)(t + 1));
        }
    } else {
        // ========================= P1 role ==================================
        const int c1 = lrank - 20;
        const int col0 = c1 * 64;

        s16x8 ghi[4][6], glo[4][6];      // W_hh2 fragments
#pragma unroll
        for (int nt = 0; nt < 4; nt++)
#pragma unroll
            for (int ks = 0; ks < 6; ks++)
                load_wfrag(Whh2, col0 + nt * 16 + l15, kb0 + ks * 32 + lk8,
                           ghi[nt][ks], glo[nt][ks]);

        const int er = tid >> 4;
        const int ec0 = (tid & 15) * 4;

        for (int u = 0; u < T_LEN; u++) {
            if (u) { wait_flags(fH2, 12, (unsigned)u); acq_ag(); }

            const int hs = (u + 1) & 1;      // h2(u-1) slot
            const unsigned short* Gh = (const unsigned short*)(gb + G_H2 + hs * 2 * HB_SZ);
            const unsigned short* Gl = (const unsigned short*)(gb + G_H2 + hs * 2 * HB_SZ + HB_SZ);
            s16x8 ah[6], al[6];
            ld6(Gh + l15 * H + kb0 + lk8, ah);
            ld6(Gl + l15 * H + kb0 + lk8, al);

            fx4 a2[4];
#pragma unroll
            for (int nt = 0; nt < 4; nt++) a2[nt] = fx4{0.f, 0.f, 0.f, 0.f};
#pragma unroll
            for (int ks = 0; ks < 6; ks++)
#pragma unroll
                for (int nt = 0; nt < 4; nt++) {
                    a2[nt] = mfma16(ah[ks], ghi[nt][ks], a2[nt]);
                    a2[nt] = mfma16(ah[ks], glo[nt][ks], a2[nt]);
                    a2[nt] = mfma16(al[ks], ghi[nt][ks], a2[nt]);
                }

#pragma unroll
            for (int nt = 0; nt < 4; nt++)
#pragma unroll
                for (int i = 0; i < 4; i++)
                    red[w][(lane >> 4) * 4 + i][nt * 16 + l15] = a2[nt][i];
            __syncthreads();

            float* S1w = S1 + (u & 1) * (16 * H) + (long)er * H + col0 + ec0;
#pragma unroll
            for (int j = 0; j < 4; j++) {
                int cc = ec0 + j;
                float s = red[0][er][cc] + red[1][er][cc] + red[2][er][cc] + red[3][er][cc];
                st_ag((unsigned*)(S1w + j), __float_as_uint(s));
            }

            DRAIN();
            if (tid == 0) st_ag(fS1 + c1, (unsigned)(u + 1));
        }
    }
}

extern "C" void kernel_launch(void* const* d_in, const int* in_sizes, int n_in,
                              void* d_out, int out_size, void* d_ws, size_t ws_size,
                              hipStream_t stream) {
    const float* x    = (const float*)d_in[0];
    const float* Wih1 = (const float*)d_in[1];
    const float* Whh1 = (const float*)d_in[2];
    const float* bih1 = (const float*)d_in[3];
    const float* bhh1 = (const float*)d_in[4];
    const float* Wih2 = (const float*)d_in[5];
    const float* Whh2 = (const float*)d_in[6];
    const float* bih2 = (const float*)d_in[7];
    const float* bhh2 = (const float*)d_in[8];
    const float* Wlin = (const float*)d_in[9];
    const float* blin = (const float*)d_in[10];

    // Zero flags + h-state (initial h = 0).  S1/P fully written before read;
    // out fully overwritten by owned stores.
    hipMemsetAsync(d_ws, 0, WS_TOTAL, stream);

    rnn_persist<<<NWG, 256, 0, stream>>>(x, Wih1, Whh1, bih1, bhh1,
                                         Wih2, Whh2, bih2, bhh2,
                                         Wlin, blin, (float*)d_out,
                                         (unsigned char*)d_ws);
}

// Round 9
// 13438.359 us; speedup vs baseline: 1.1860x; 1.1860x over previous
//
#include <hip/hip_runtime.h>
#include <math.h>

// ---------------------------------------------------------------------------
// 2-layer tanh RNN scan, B=128, T=1024, H=768.  Persistent kernel, 256 WGs.
// Round-9: r7's merged L2 role (both matmuls in one WG) + r8's off-path
// anti-deps, with the L1<->L2 interlock REMOVED from the critical chain:
//   * fP1 flag eliminated: h1 is 4-slot; L1's overwrite gate (fH2 >= t-3) is
//     pre-established by the off-path out-reduce gate (fH2 >= t-2) of the
//     previous iteration -> L1 loop has ONE detect (its own fL1 chain).
//   * L2 loop: ONE real detect (fH2 >= t) + near-free fL1 >= t+1 check, one
//     acquire fence, then ALL 24 fragment loads (h2(t-1) + h1(t)) issued
//     back-to-back so they share one latency window, 72 MFMA, epilogue,
//     flag fH2.  No mid-loop flag stores.
// Coherence primitives: r2/r3/r7-proven agent-scope only (st_ag sc0 sc1
// write-through, ld_ag coherent load, one agent acquire fence per step,
// then plain cached bulk loads).  Numerics: bf16 (hi,lo), 3-product MFMA.
//
// Roles per group (32 WGs, 16 batch rows): lrank 0..7 = L1 (96 cols of
// W_hh1); lrank 8..31 = L2 (32 cols of W_ih2+W_hh2).
// Dep graph (all edges verified):
//   L2 step t reads h2(t-1)    <- fH2 >= t   (waited)
//   L2 step t reads h1(t)      <- fL1 >= t+1 (waited, usually instant)
//   L2 step t overwrites h2(t-2) slot        <- fH2 >= t (same wait)
//   L2 step t writes P slot t&3; L1 reads P(t-3) at step t; collision
//     writer u=t+1 gated by fL1 >= t+2 (L1 past its step-t read).  safe
//   L1 step t reads h1(t-1)    <- fL1 >= t   (waited, own chain)
//   L1 step t stores h1(t) slot t&3; readers of h1(t-4) done when
//     fH2 >= t-3  <- established by step t-1's out-gate (fH2 >= t-3). safe
//   L1 step t out-reduce P(t-3) <- fH2 >= t-2 (off-path cached wait)
//   tail: fH2 >= T covers P(T-3..T-1)
// ---------------------------------------------------------------------------

typedef short s16x8 __attribute__((ext_vector_type(8)));
typedef float fx4   __attribute__((ext_vector_type(4)));

#define NWG    256
#define T_LEN  1024
#define H      768
#define GROUPS 8
#define GROWS  16

// per-group ws layout (bytes)
#define GRP_BASE   8192
#define G_FL1 0               // u32[8]
#define G_FH2 128             // u32[24]
#define G_PB  512             // float[4][16][2][24] = 12288B
#define G_H1  16384           // 4 slots x {hi,lo} x 24576B = 196608
#define G_H2  212992          // 2 slots x {hi,lo} x 24576B = 98304
#define GRP_STRIDE 315392
#define HB_SZ 24576
#define WS_TOTAL (GRP_BASE + GROUPS * GRP_STRIDE)

__device__ __forceinline__ unsigned short f2bf(float x) {
    unsigned u = __float_as_uint(x);
    unsigned r = (u + 0x7FFFu + ((u >> 16) & 1u)) >> 16;   // RNE
    return (unsigned short)r;
}
__device__ __forceinline__ float bf2f(unsigned short b) {
    return __uint_as_float(((unsigned)b) << 16);
}
__device__ __forceinline__ fx4 mfma16(s16x8 a, s16x8 b, fx4 c) {
    return __builtin_amdgcn_mfma_f32_16x16x32_bf16(a, b, c, 0, 0, 0);
}

// ---- proven agent-scope primitives -----------------------------------------
__device__ __forceinline__ void st_ag(unsigned* p, unsigned v) {
    __hip_atomic_store(p, v, __ATOMIC_RELAXED, __HIP_MEMORY_SCOPE_AGENT);
}
__device__ __forceinline__ unsigned ld_ag(const unsigned* p) {
    return __hip_atomic_load(p, __ATOMIC_RELAXED, __HIP_MEMORY_SCOPE_AGENT);
}
__device__ __forceinline__ void acq_ag() {
    __builtin_amdgcn_fence(__ATOMIC_ACQUIRE, "agent");
}

__device__ __forceinline__ void load_wfrag(const float* __restrict__ W,
                                           int col, int kk, s16x8& hi, s16x8& lo) {
    const float* p = W + (long)col * H + kk;
#pragma unroll
    for (int j = 0; j < 8; j++) {
        float w = p[j];
        unsigned short h = f2bf(w);
        float r = w - bf2f(h);
        hi[j] = (short)h;
        lo[j] = (short)f2bf(r);
    }
}

__device__ __forceinline__ void ld6(const unsigned short* p, s16x8 (&d)[6]) {
#pragma unroll
    for (int ks = 0; ks < 6; ks++)
        d[ks] = *reinterpret_cast<const s16x8*>(p + ks * 32);
}

__device__ __forceinline__ unsigned wave_min(unsigned v) {
#pragma unroll
    for (int o = 32; o; o >>= 1) {
        unsigned u = (unsigned)__shfl_xor((int)v, o);
        v = v < u ? v : u;
    }
    return v;
}

// Wave-independent flag wait (no fence, no syncthreads).
__device__ __forceinline__ unsigned wait_flags(const unsigned* f, int n, unsigned T) {
    int l = (int)(threadIdx.x & 63); if (l >= n) l = n - 1;
    unsigned m;
    long spin = 0;
    for (;;) {
        m = wave_min(ld_ag(f + l));
        if (m >= T) break;
        __builtin_amdgcn_s_sleep(1);
        if (++spin > (1L << 20)) break;   // failsafe
    }
    return m;
}

#define DRAIN() do { asm volatile("s_waitcnt vmcnt(0)" ::: "memory"); __syncthreads(); } while (0)

__global__ __launch_bounds__(256, 1) void rnn_persist(
    const float* __restrict__ x,
    const float* __restrict__ Wih1, const float* __restrict__ Whh1,
    const float* __restrict__ bih1, const float* __restrict__ bhh1,
    const float* __restrict__ Wih2, const float* __restrict__ Whh2,
    const float* __restrict__ bih2, const float* __restrict__ bhh2,
    const float* __restrict__ Wlin, const float* __restrict__ blin,
    float* __restrict__ out, unsigned char* __restrict__ ws)
{
    const int wg = blockIdx.x;
    const int tid = threadIdx.x;
    const int lane = tid & 63;
    const int w = tid >> 6;          // wave 0..3, K range [w*192, +192)
    const int l15 = lane & 15;
    const int lk8 = (lane >> 4) * 8;

    const int group = wg >> 5;       // 0..7
    const int lrank = wg & 31;       // 0..31

    __shared__ float red[4][16][97];

    unsigned char* gb = ws + GRP_BASE + (size_t)group * GRP_STRIDE;
    unsigned* fL1 = (unsigned*)(gb + G_FL1);
    unsigned* fH2 = (unsigned*)(gb + G_FH2);
    float*    Pb  = (float*)(gb + G_PB);       // [4][16][2][24]

    const int kb0 = w * 192;

    if (lrank < 8) {
        // ========================= L1 role ==================================
        const int c = lrank;
        const int col0 = c * 96;

        s16x8 whi[6][6], wlo[6][6];
#pragma unroll
        for (int ks = 0; ks < 6; ks++)
#pragma unroll
            for (int nt = 0; nt < 6; nt++)
                load_wfrag(Whh1, col0 + nt * 16 + l15, kb0 + ks * 32 + lk8,
                           whi[ks][nt], wlo[ks][nt]);

        const int er = tid >> 4;                // row 0..15
        const int ec0 = (tid & 15) * 6;         // 6 consecutive cols
        const int b = group * GROWS + er;
        float bs[6], wi0[6], wi1[6];
#pragma unroll
        for (int j = 0; j < 6; j++) {
            int cg = col0 + ec0 + j;
            bs[j] = bih1[cg] + bhh1[cg];
            wi0[j] = Wih1[cg * 2 + 0];
            wi1[j] = Wih1[cg * 2 + 1];
        }
        const int ov = tid >> 5;                // 0..3 (tid<128)
        const int oj = tid & 31;
        const int orow = 2 * c + (ov >> 1);
        const int ooo = ov & 1;
        const float blv = blin[ooo];

        unsigned fH2c = 0;

        for (int t = 0; t < T_LEN; t++) {
            const int rs = (t + 3) & 3;         // h1(t-1) slot
            const int wsl = t & 3;              // h1(t) slot
            float x0 = x[b * 2048 + t];
            float x1 = x[b * 2048 + 1024 + t];

            if (t) { wait_flags(fL1, 8, (unsigned)t); acq_ag(); }

            const unsigned short* Hh = (const unsigned short*)(gb + G_H1 + rs * 2 * HB_SZ);
            const unsigned short* Hl = (const unsigned short*)(gb + G_H1 + rs * 2 * HB_SZ + HB_SZ);
            s16x8 ah[6], al[6];
            ld6(Hh + l15 * H + kb0 + lk8, ah);
            ld6(Hl + l15 * H + kb0 + lk8, al);

            fx4 acc[6];
#pragma unroll
            for (int nt = 0; nt < 6; nt++) acc[nt] = fx4{0.f, 0.f, 0.f, 0.f};
#pragma unroll
            for (int ks = 0; ks < 6; ks++)
#pragma unroll
                for (int nt = 0; nt < 6; nt++) {
                    acc[nt] = mfma16(ah[ks], whi[ks][nt], acc[nt]);
                    acc[nt] = mfma16(ah[ks], wlo[ks][nt], acc[nt]);
                    acc[nt] = mfma16(al[ks], whi[ks][nt], acc[nt]);
                }

#pragma unroll
            for (int nt = 0; nt < 6; nt++)
#pragma unroll
                for (int i = 0; i < 4; i++)
                    red[w][(lane >> 4) * 4 + i][nt * 16 + l15] = acc[nt][i];
            __syncthreads();

            unsigned hw[3], lw[3];
#pragma unroll
            for (int jj = 0; jj < 3; jj++) {
                unsigned hp = 0, lp = 0;
#pragma unroll
                for (int k = 0; k < 2; k++) {
                    int j = jj * 2 + k;
                    int cc = ec0 + j;
                    float v = red[0][er][cc] + red[1][er][cc] + red[2][er][cc] + red[3][er][cc];
                    v += x0 * wi0[j] + x1 * wi1[j] + bs[j];
                    v = tanhf(v);
                    unsigned short hb = f2bf(v);
                    unsigned short lb = f2bf(v - bf2f(hb));
                    hp |= ((unsigned)hb) << (16 * k);
                    lp |= ((unsigned)lb) << (16 * k);
                }
                hw[jj] = hp; lw[jj] = lp;
            }

            // slot-overwrite gate fH2 >= t-3: established by step t-1's
            // out-gate (fH2 >= t-3).  No wait here.
            unsigned* Dh = (unsigned*)(gb + G_H1 + wsl * 2 * HB_SZ) + ((long)er * H + col0 + ec0) / 2;
            unsigned* Dl = (unsigned*)(gb + G_H1 + wsl * 2 * HB_SZ + HB_SZ) + ((long)er * H + col0 + ec0) / 2;
            st_ag(Dh + 0, hw[0]); st_ag(Dh + 1, hw[1]); st_ag(Dh + 2, hw[2]);
            st_ag(Dl + 0, lw[0]); st_ag(Dl + 1, lw[1]); st_ag(Dl + 2, lw[2]);

            DRAIN();
            if (tid == 0) st_ag(fL1 + c, (unsigned)(t + 1));

            // Off-path: out(t-3) reduce; its gate also pre-establishes the
            // h1 slot-overwrite gate for step t+1.
            if (t >= 3) {
                if (fH2c < (unsigned)(t - 2)) fH2c = wait_flags(fH2, 24, (unsigned)(t - 2));
                if (tid < 128) {
                    float p = 0.f;
                    if (oj < 24)
                        p = __uint_as_float(ld_ag((const unsigned*)
                            (Pb + ((((t - 3) & 3) * 16 + orow) * 2 + ooo) * 24 + oj)));
#pragma unroll
                    for (int o = 16; o; o >>= 1) p += __shfl_down(p, o, 32);
                    if (oj == 0) out[(group * GROWS + orow) * 2048 + ooo * 1024 + (t - 3)] = p + blv;
                }
            }
        }

        // tail: P(T-3), P(T-2), P(T-1)
        wait_flags(fH2, 24, (unsigned)T_LEN);
        if (tid < 128) {
#pragma unroll
            for (int par = 0; par < 3; par++) {
                int tt = T_LEN - 3 + par;
                float p = 0.f;
                if (oj < 24)
                    p = __uint_as_float(ld_ag((const unsigned*)
                        (Pb + (((tt & 3) * 16 + orow) * 2 + ooo) * 24 + oj)));
#pragma unroll
                for (int o = 16; o; o >>= 1) p += __shfl_down(p, o, 32);
                if (oj == 0) out[(group * GROWS + orow) * 2048 + ooo * 1024 + tt] = p + blv;
            }
        }
    } else {
        // ========================= L2 role ==================================
        const int q = lrank - 8;         // 0..23
        const int col0 = q * 32;

        s16x8 ghi[2][6], glo[2][6], ihi[2][6], ilo[2][6];
#pragma unroll
        for (int nt = 0; nt < 2; nt++)
#pragma unroll
            for (int ks = 0; ks < 6; ks++) {
                load_wfrag(Whh2, col0 + nt * 16 + l15, kb0 + ks * 32 + lk8, ghi[nt][ks], glo[nt][ks]);
                load_wfrag(Wih2, col0 + nt * 16 + l15, kb0 + ks * 32 + lk8, ihi[nt][ks], ilo[nt][ks]);
            }

        const int er = tid >> 4;             // 0..15
        const int ec0 = (tid & 15) * 2;      // 0..30
        const float bsA = bih2[col0 + ec0] + bhh2[col0 + ec0];
        const float bsB = bih2[col0 + ec0 + 1] + bhh2[col0 + ec0 + 1];

        const int ro = tid >> 1, oo = tid & 1;   // tid<32: out-partial dot
        float wl[32];
        if (tid < 32) {
#pragma unroll
            for (int cc = 0; cc < 32; cc++) wl[cc] = Wlin[oo * H + col0 + cc];
        }

        for (int t = 0; t < T_LEN; t++) {
            const int rb = (t + 1) & 1;     // h2(t-1) slot
            const int wb = t & 1;           // h2(t) slot
            const int hs = t & 3;           // h1(t) slot

            if (t) wait_flags(fH2, 24, (unsigned)t);        // h2(t-1) ready
            wait_flags(fL1, 8, (unsigned)(t + 1));          // h1(t) ready (ahead)
            acq_ag();

            // All 24 fragment loads issued together (one latency window).
            const unsigned short* Gh = (const unsigned short*)(gb + G_H2 + rb * 2 * HB_SZ);
            const unsigned short* Gl = (const unsigned short*)(gb + G_H2 + rb * 2 * HB_SZ + HB_SZ);
            const unsigned short* Hh = (const unsigned short*)(gb + G_H1 + hs * 2 * HB_SZ);
            const unsigned short* Hl = (const unsigned short*)(gb + G_H1 + hs * 2 * HB_SZ + HB_SZ);
            s16x8 ah[6], al[6], bh[6], bl[6];
            ld6(Gh + l15 * H + kb0 + lk8, ah);
            ld6(Gl + l15 * H + kb0 + lk8, al);
            ld6(Hh + l15 * H + kb0 + lk8, bh);
            ld6(Hl + l15 * H + kb0 + lk8, bl);

            fx4 a2[2];
            a2[0] = fx4{0.f, 0.f, 0.f, 0.f};
            a2[1] = fx4{0.f, 0.f, 0.f, 0.f};
#pragma unroll
            for (int ks = 0; ks < 6; ks++)
#pragma unroll
                for (int nt = 0; nt < 2; nt++) {
                    a2[nt] = mfma16(ah[ks], ghi[nt][ks], a2[nt]);
                    a2[nt] = mfma16(ah[ks], glo[nt][ks], a2[nt]);
                    a2[nt] = mfma16(al[ks], ghi[nt][ks], a2[nt]);
                }
#pragma unroll
            for (int ks = 0; ks < 6; ks++)
#pragma unroll
                for (int nt = 0; nt < 2; nt++) {
                    a2[nt] = mfma16(bh[ks], ihi[nt][ks], a2[nt]);
                    a2[nt] = mfma16(bh[ks], ilo[nt][ks], a2[nt]);
                    a2[nt] = mfma16(bl[ks], ihi[nt][ks], a2[nt]);
                }

#pragma unroll
            for (int nt = 0; nt < 2; nt++)
#pragma unroll
                for (int i = 0; i < 4; i++)
                    red[w][(lane >> 4) * 4 + i][nt * 16 + l15] = a2[nt][i];
            __syncthreads();

            float v0 = red[0][er][ec0] + red[1][er][ec0] + red[2][er][ec0] + red[3][er][ec0] + bsA;
            float v1 = red[0][er][ec0 + 1] + red[1][er][ec0 + 1] + red[2][er][ec0 + 1] + red[3][er][ec0 + 1] + bsB;
            v0 = tanhf(v0); v1 = tanhf(v1);
            unsigned short hb0 = f2bf(v0), hb1 = f2bf(v1);
            unsigned hp = ((unsigned)hb0) | (((unsigned)hb1) << 16);
            unsigned lp = ((unsigned)f2bf(v0 - bf2f(hb0))) | (((unsigned)f2bf(v1 - bf2f(hb1))) << 16);
            unsigned* Dh = (unsigned*)(gb + G_H2 + wb * 2 * HB_SZ) + ((long)er * H + col0 + ec0) / 2;
            unsigned* Dl = (unsigned*)(gb + G_H2 + wb * 2 * HB_SZ + HB_SZ) + ((long)er * H + col0 + ec0) / 2;
            st_ag(Dh, hp);
            st_ag(Dl, lp);
            red[0][er][ec0] = v0;
            red[0][er][ec0 + 1] = v1;
            __syncthreads();

            if (tid < 32) {
                float s = 0.f;
#pragma unroll
                for (int cc = 0; cc < 32; cc++) s += red[0][ro][cc] * wl[cc];
                st_ag((unsigned*)&Pb[(((t & 3) * 16 + ro) * 2 + oo) * 24 + q],
                      __float_as_uint(s));
            }

            DRAIN();
            if (tid == 0) st_ag(fH2 + q, (unsigned)(t + 1));
        }
    }
}

extern "C" void kernel_launch(void* const* d_in, const int* in_sizes, int n_in,
                              void* d_out, int out_size, void* d_ws, size_t ws_size,
                              hipStream_t stream) {
    const float* x    = (const float*)d_in[0];
    const float* Wih1 = (const float*)d_in[1];
    const float* Whh1 = (const float*)d_in[2];
    const float* bih1 = (const float*)d_in[3];
    const float* bhh1 = (const float*)d_in[4];
    const float* Wih2 = (const float*)d_in[5];
    const float* Whh2 = (const float*)d_in[6];
    const float* bih2 = (const float*)d_in[7];
    const float* bhh2 = (const float*)d_in[8];
    const float* Wlin = (const float*)d_in[9];
    const float* blin = (const float*)d_in[10];

    // Zero flags + h-state (initial h = 0).  P fully written before read;
    // out fully overwritten by owned stores.
    hipMemsetAsync(d_ws, 0, WS_TOTAL, stream);

    rnn_persist<<<NWG, 256, 0, stream>>>(x, Wih1, Whh1, bih1, bhh1,
                                         Wih2, Whh2, bih2, bhh2,
                                         Wlin, blin, (float*)d_out,
                                         (unsigned char*)d_ws);
}

// Round 10
// 9586.927 us; speedup vs baseline: 1.6625x; 1.4017x over previous
//
#include <hip/hip_runtime.h>
#include <math.h>

// ---------------------------------------------------------------------------
// 2-layer tanh RNN scan, B=128, T=1024, H=768.  Persistent kernel, 256 WGs.
// Round-10 = round-7's PROVEN schedule (wave-0 polls + syncthreads; L2
// phase-1 overlaps the h1 wait) with three deltas:
//   * fP1 flag deleted.  h1 is 4-slot; L1's slot-overwrite gate (fH2>=t-2)
//     is the off-path out-reduce gate, moved to the TOP of L1's loop.
//   * L2 loses the mid-loop DRAIN+flag (one fewer serial window).
//   * P buffer 4-slot; out(t-3) reduced by L1 at top of iter t.
// Coherence: r2/r3/r7-proven agent-scope only (st_ag sc0 sc1 write-through;
// ld_ag coherent load; wave-0 flag poll + one agent acquire fence + sync;
// plain cached bulk loads after the fence).  Numerics: bf16 (hi,lo) pairs,
// 3-product MFMA, fp32 accumulate.
//
// Roles per group (32 WGs, 16 batch rows): lrank 0..7 = L1 (96 cols W_hh1),
// lrank 8..31 = L2 (32 cols of W_ih2 + W_hh2).
// Dep graph (verified):
//   L1 iter t: [t>=3: gate fH2>=t-2 (no acq), out(t-3) via ld_ag P]
//              wait fL1>=t (acq) -> read h1(t-1) slot (t-1)&3 -> compute ->
//              store h1(t) slot t&3 (overwrite h1(t-4): needs fH2>=t-3,
//              have fH2>=t-2 from this iter's gate) -> DRAIN -> fL1=t+1.
//   L2 iter t: wait fH2>=t (acq; peers' step t-1 done => h2(t-2) slot free,
//              h2(t-1) readable) -> phase1 MFMA -> wait fL1>=t+1 (acq) ->
//              read h1(t) -> phase3 -> h2(t) slot t&1, P slot t&3
//              (P(t-4) overwrite safe: L1 read it at iter t-1 before
//              flagging fL1=t, and this write is gated on fL1>=t+1) ->
//              DRAIN -> fH2=t+1.
//   tail: fH2>=T covers P(T-3), P(T-2), P(T-1).
// ---------------------------------------------------------------------------

typedef short s16x8 __attribute__((ext_vector_type(8)));
typedef float fx4   __attribute__((ext_vector_type(4)));

#define NWG    256
#define T_LEN  1024
#define H      768
#define GROUPS 8
#define GROWS  16

// per-group ws layout (bytes)
#define GRP_BASE   8192
#define G_FL1 0               // u32[8]
#define G_FH2 128             // u32[24]
#define G_PB  512             // float[4][16][2][24] = 12288B
#define G_H1  16384           // 4 slots x {hi,lo} x 24576B
#define G_H2  212992          // 2 slots x {hi,lo} x 24576B
#define GRP_STRIDE 315392
#define HB_SZ 24576
#define WS_TOTAL (GRP_BASE + GROUPS * GRP_STRIDE)

__device__ __forceinline__ unsigned short f2bf(float x) {
    unsigned u = __float_as_uint(x);
    unsigned r = (u + 0x7FFFu + ((u >> 16) & 1u)) >> 16;   // RNE
    return (unsigned short)r;
}
__device__ __forceinline__ float bf2f(unsigned short b) {
    return __uint_as_float(((unsigned)b) << 16);
}
__device__ __forceinline__ fx4 mfma16(s16x8 a, s16x8 b, fx4 c) {
    return __builtin_amdgcn_mfma_f32_16x16x32_bf16(a, b, c, 0, 0, 0);
}

// ---- proven agent-scope primitives -----------------------------------------
__device__ __forceinline__ void st_ag(unsigned* p, unsigned v) {
    __hip_atomic_store(p, v, __ATOMIC_RELAXED, __HIP_MEMORY_SCOPE_AGENT);
}
__device__ __forceinline__ unsigned ld_ag(const unsigned* p) {
    return __hip_atomic_load(p, __ATOMIC_RELAXED, __HIP_MEMORY_SCOPE_AGENT);
}
__device__ __forceinline__ void acq_ag() {
    __builtin_amdgcn_fence(__ATOMIC_ACQUIRE, "agent");
}

__device__ __forceinline__ void load_wfrag(const float* __restrict__ W,
                                           int col, int kk, s16x8& hi, s16x8& lo) {
    const float* p = W + (long)col * H + kk;
#pragma unroll
    for (int j = 0; j < 8; j++) {
        float w = p[j];
        unsigned short h = f2bf(w);
        float r = w - bf2f(h);
        hi[j] = (short)h;
        lo[j] = (short)f2bf(r);
    }
}

__device__ __forceinline__ void ld6(const unsigned short* p, s16x8 (&d)[6]) {
#pragma unroll
    for (int ks = 0; ks < 6; ks++)
        d[ks] = *reinterpret_cast<const s16x8*>(p + ks * 32);
}

__device__ __forceinline__ unsigned wave_min(unsigned v) {
#pragma unroll
    for (int o = 32; o; o >>= 1) {
        unsigned u = (unsigned)__shfl_xor((int)v, o);
        v = v < u ? v : u;
    }
    return v;
}

// r7-proven wait: wave 0 polls, optional tid0 acquire fence, syncthreads.
__device__ __forceinline__ void waitn(const unsigned* f, int n, unsigned T,
                                      int tid, bool acq) {
    if (tid < 64) {
        int l = tid < n ? tid : n - 1;
        long spin = 0;
        for (;;) {
            if (wave_min(ld_ag(f + l)) >= T) break;
            __builtin_amdgcn_s_sleep(1);
            if (++spin > (1L << 20)) break;   // failsafe
        }
    }
    if (acq && tid == 0) acq_ag();
    __syncthreads();
}

#define DRAIN() do { asm volatile("s_waitcnt vmcnt(0)" ::: "memory"); __syncthreads(); } while (0)

__global__ __launch_bounds__(256, 1) void rnn_persist(
    const float* __restrict__ x,
    const float* __restrict__ Wih1, const float* __restrict__ Whh1,
    const float* __restrict__ bih1, const float* __restrict__ bhh1,
    const float* __restrict__ Wih2, const float* __restrict__ Whh2,
    const float* __restrict__ bih2, const float* __restrict__ bhh2,
    const float* __restrict__ Wlin, const float* __restrict__ blin,
    float* __restrict__ out, unsigned char* __restrict__ ws)
{
    const int wg = blockIdx.x;
    const int tid = threadIdx.x;
    const int lane = tid & 63;
    const int w = tid >> 6;          // wave 0..3, K range [w*192, +192)
    const int l15 = lane & 15;
    const int lk8 = (lane >> 4) * 8;

    const int group = wg >> 5;       // 0..7
    const int lrank = wg & 31;       // 0..31

    __shared__ float red[4][16][97];

    unsigned char* gb = ws + GRP_BASE + (size_t)group * GRP_STRIDE;
    unsigned* fL1 = (unsigned*)(gb + G_FL1);
    unsigned* fH2 = (unsigned*)(gb + G_FH2);
    float*    Pb  = (float*)(gb + G_PB);       // [4][16][2][24]

    const int kb0 = w * 192;

    if (lrank < 8) {
        // ========================= L1 role ==================================
        const int c = lrank;
        const int col0 = c * 96;

        s16x8 whi[6][6], wlo[6][6];
#pragma unroll
        for (int ks = 0; ks < 6; ks++)
#pragma unroll
            for (int nt = 0; nt < 6; nt++)
                load_wfrag(Whh1, col0 + nt * 16 + l15, kb0 + ks * 32 + lk8,
                           whi[ks][nt], wlo[ks][nt]);

        const int er = tid >> 4;                // row 0..15
        const int ec0 = (tid & 15) * 6;         // 6 consecutive cols
        const int b = group * GROWS + er;
        float bs[6], wi0[6], wi1[6];
#pragma unroll
        for (int j = 0; j < 6; j++) {
            int cg = col0 + ec0 + j;
            bs[j] = bih1[cg] + bhh1[cg];
            wi0[j] = Wih1[cg * 2 + 0];
            wi1[j] = Wih1[cg * 2 + 1];
        }
        const int ov = tid >> 5;                // 0..3 (tid<128)
        const int oj = tid & 31;
        const int orow = 2 * c + (ov >> 1);
        const int ooo = ov & 1;
        const float blv = blin[ooo];

        for (int t = 0; t < T_LEN; t++) {
            const int rs = (t + 3) & 3;         // h1(t-1) slot
            const int wsl = t & 3;              // h1(t) slot
            float x0 = x[b * 2048 + t];
            float x1 = x[b * 2048 + 1024 + t];

            // Top-of-iter off-path: gate (also h1-slot-overwrite guard) +
            // out(t-3) reduce.  No acquire: P read via coherent ld_ag.
            if (t >= 3) {
                waitn(fH2, 24, (unsigned)(t - 2), tid, false);
                if (tid < 128) {
                    float p = 0.f;
                    if (oj < 24)
                        p = __uint_as_float(ld_ag((const unsigned*)
                            (Pb + ((((t - 3) & 3) * 16 + orow) * 2 + ooo) * 24 + oj)));
#pragma unroll
                    for (int o = 16; o; o >>= 1) p += __shfl_down(p, o, 32);
                    if (oj == 0) out[(group * GROWS + orow) * 2048 + ooo * 1024 + (t - 3)] = p + blv;
                }
            }

            if (t) waitn(fL1, 8, (unsigned)t, tid, true);   // h1(t-1) ready

            const unsigned short* Hh = (const unsigned short*)(gb + G_H1 + rs * 2 * HB_SZ);
            const unsigned short* Hl = (const unsigned short*)(gb + G_H1 + rs * 2 * HB_SZ + HB_SZ);
            s16x8 ah[6], al[6];
            ld6(Hh + l15 * H + kb0 + lk8, ah);
            ld6(Hl + l15 * H + kb0 + lk8, al);

            fx4 acc[6];
#pragma unroll
            for (int nt = 0; nt < 6; nt++) acc[nt] = fx4{0.f, 0.f, 0.f, 0.f};
#pragma unroll
            for (int ks = 0; ks < 6; ks++)
#pragma unroll
                for (int nt = 0; nt < 6; nt++) {
                    acc[nt] = mfma16(ah[ks], whi[ks][nt], acc[nt]);
                    acc[nt] = mfma16(ah[ks], wlo[ks][nt], acc[nt]);
                    acc[nt] = mfma16(al[ks], whi[ks][nt], acc[nt]);
                }

#pragma unroll
            for (int nt = 0; nt < 6; nt++)
#pragma unroll
                for (int i = 0; i < 4; i++)
                    red[w][(lane >> 4) * 4 + i][nt * 16 + l15] = acc[nt][i];
            __syncthreads();

            unsigned hw[3], lw[3];
#pragma unroll
            for (int jj = 0; jj < 3; jj++) {
                unsigned hp = 0, lp = 0;
#pragma unroll
                for (int k = 0; k < 2; k++) {
                    int j = jj * 2 + k;
                    int cc = ec0 + j;
                    float v = red[0][er][cc] + red[1][er][cc] + red[2][er][cc] + red[3][er][cc];
                    v += x0 * wi0[j] + x1 * wi1[j] + bs[j];
                    v = tanhf(v);
                    unsigned short hb = f2bf(v);
                    unsigned short lb = f2bf(v - bf2f(hb));
                    hp |= ((unsigned)hb) << (16 * k);
                    lp |= ((unsigned)lb) << (16 * k);
                }
                hw[jj] = hp; lw[jj] = lp;
            }

            unsigned* Dh = (unsigned*)(gb + G_H1 + wsl * 2 * HB_SZ) + ((long)er * H + col0 + ec0) / 2;
            unsigned* Dl = (unsigned*)(gb + G_H1 + wsl * 2 * HB_SZ + HB_SZ) + ((long)er * H + col0 + ec0) / 2;
            st_ag(Dh + 0, hw[0]); st_ag(Dh + 1, hw[1]); st_ag(Dh + 2, hw[2]);
            st_ag(Dl + 0, lw[0]); st_ag(Dl + 1, lw[1]); st_ag(Dl + 2, lw[2]);

            DRAIN();
            if (tid == 0) st_ag(fL1 + c, (unsigned)(t + 1));
        }

        // tail: P(T-3), P(T-2), P(T-1)
        waitn(fH2, 24, (unsigned)T_LEN, tid, false);
        if (tid < 128) {
#pragma unroll
            for (int par = 0; par < 3; par++) {
                int tt = T_LEN - 3 + par;
                float p = 0.f;
                if (oj < 24)
                    p = __uint_as_float(ld_ag((const unsigned*)
                        (Pb + (((tt & 3) * 16 + orow) * 2 + ooo) * 24 + oj)));
#pragma unroll
                for (int o = 16; o; o >>= 1) p += __shfl_down(p, o, 32);
                if (oj == 0) out[(group * GROWS + orow) * 2048 + ooo * 1024 + tt] = p + blv;
            }
        }
    } else {
        // ========================= L2 role ==================================
        const int q = lrank - 8;         // 0..23
        const int col0 = q * 32;

        s16x8 ghi[2][6], glo[2][6], ihi[2][6], ilo[2][6];
#pragma unroll
        for (int nt = 0; nt < 2; nt++)
#pragma unroll
            for (int ks = 0; ks < 6; ks++) {
                load_wfrag(Whh2, col0 + nt * 16 + l15, kb0 + ks * 32 + lk8, ghi[nt][ks], glo[nt][ks]);
                load_wfrag(Wih2, col0 + nt * 16 + l15, kb0 + ks * 32 + lk8, ihi[nt][ks], ilo[nt][ks]);
            }

        const int er = tid >> 4;             // 0..15
        const int ec0 = (tid & 15) * 2;      // 0..30
        const float bsA = bih2[col0 + ec0] + bhh2[col0 + ec0];
        const float bsB = bih2[col0 + ec0 + 1] + bhh2[col0 + ec0 + 1];

        const int ro = tid >> 1, oo = tid & 1;   // tid<32: out-partial dot
        float wl[32];
        if (tid < 32) {
#pragma unroll
            for (int cc = 0; cc < 32; cc++) wl[cc] = Wlin[oo * H + col0 + cc];
        }

        for (int t = 0; t < T_LEN; t++) {
            const int rb = (t + 1) & 1;     // h2(t-1) slot
            const int wb = t & 1;           // h2(t) slot
            const int hs = t & 3;           // h1(t) slot

            if (t) waitn(fH2, 24, (unsigned)t, tid, true);   // h2(t-1) ready

            // phase 1: h2(t-1) @ W_hh2^T (overlaps h1(t) production)
            const unsigned short* Gh = (const unsigned short*)(gb + G_H2 + rb * 2 * HB_SZ);
            const unsigned short* Gl = (const unsigned short*)(gb + G_H2 + rb * 2 * HB_SZ + HB_SZ);
            s16x8 ah[6], al[6];
            ld6(Gh + l15 * H + kb0 + lk8, ah);
            ld6(Gl + l15 * H + kb0 + lk8, al);

            fx4 a2[2];
            a2[0] = fx4{0.f, 0.f, 0.f, 0.f};
            a2[1] = fx4{0.f, 0.f, 0.f, 0.f};
#pragma unroll
            for (int ks = 0; ks < 6; ks++)
#pragma unroll
                for (int nt = 0; nt < 2; nt++) {
                    a2[nt] = mfma16(ah[ks], ghi[nt][ks], a2[nt]);
                    a2[nt] = mfma16(ah[ks], glo[nt][ks], a2[nt]);
                    a2[nt] = mfma16(al[ks], ghi[nt][ks], a2[nt]);
                }

            waitn(fL1, 8, (unsigned)(t + 1), tid, true);     // h1(t) ready

            // phase 3: += h1(t) @ W_ih2^T
            const unsigned short* Hh = (const unsigned short*)(gb + G_H1 + hs * 2 * HB_SZ);
            const unsigned short* Hl = (const unsigned short*)(gb + G_H1 + hs * 2 * HB_SZ + HB_SZ);
            ld6(Hh + l15 * H + kb0 + lk8, ah);
            ld6(Hl + l15 * H + kb0 + lk8, al);
#pragma unroll
            for (int ks = 0; ks < 6; ks++)
#pragma unroll
                for (int nt = 0; nt < 2; nt++) {
                    a2[nt] = mfma16(ah[ks], ihi[nt][ks], a2[nt]);
                    a2[nt] = mfma16(ah[ks], ilo[nt][ks], a2[nt]);
                    a2[nt] = mfma16(al[ks], ihi[nt][ks], a2[nt]);
                }

#pragma unroll
            for (int nt = 0; nt < 2; nt++)
#pragma unroll
                for (int i = 0; i < 4; i++)
                    red[w][(lane >> 4) * 4 + i][nt * 16 + l15] = a2[nt][i];
            __syncthreads();

            float v0 = red[0][er][ec0] + red[1][er][ec0] + red[2][er][ec0] + red[3][er][ec0] + bsA;
            float v1 = red[0][er][ec0 + 1] + red[1][er][ec0 + 1] + red[2][er][ec0 + 1] + red[3][er][ec0 + 1] + bsB;
            v0 = tanhf(v0); v1 = tanhf(v1);
            unsigned short hb0 = f2bf(v0), hb1 = f2bf(v1);
            unsigned hp = ((unsigned)hb0) | (((unsigned)hb1) << 16);
            unsigned lp = ((unsigned)f2bf(v0 - bf2f(hb0))) | (((unsigned)f2bf(v1 - bf2f(hb1))) << 16);
            unsigned* Dh = (unsigned*)(gb + G_H2 + wb * 2 * HB_SZ) + ((long)er * H + col0 + ec0) / 2;
            unsigned* Dl = (unsigned*)(gb + G_H2 + wb * 2 * HB_SZ + HB_SZ) + ((long)er * H + col0 + ec0) / 2;
            st_ag(Dh, hp);
            st_ag(Dl, lp);
            red[0][er][ec0] = v0;
            red[0][er][ec0 + 1] = v1;
            __syncthreads();

            if (tid < 32) {
                float s = 0.f;
#pragma unroll
                for (int cc = 0; cc < 32; cc++) s += red[0][ro][cc] * wl[cc];
                st_ag((unsigned*)&Pb[(((t & 3) * 16 + ro) * 2 + oo) * 24 + q],
                      __float_as_uint(s));
            }

            DRAIN();
            if (tid == 0) st_ag(fH2 + q, (unsigned)(t + 1));
        }
    }
}

extern "C" void kernel_launch(void* const* d_in, const int* in_sizes, int n_in,
                              void* d_out, int out_size, void* d_ws, size_t ws_size,
                              hipStream_t stream) {
    const float* x    = (const float*)d_in[0];
    const float* Wih1 = (const float*)d_in[1];
    const float* Whh1 = (const float*)d_in[2];
    const float* bih1 = (const float*)d_in[3];
    const float* bhh1 = (const float*)d_in[4];
    const float* Wih2 = (const float*)d_in[5];
    const float* Whh2 = (const float*)d_in[6];
    const float* bih2 = (const float*)d_in[7];
    const float* bhh2 = (const float*)d_in[8];
    const float* Wlin = (const float*)d_in[9];
    const float* blin = (const float*)d_in[10];

    // Zero flags + h-state (initial h = 0).  P fully written before read;
    // out fully overwritten by owned stores.
    hipMemsetAsync(d_ws, 0, WS_TOTAL, stream);

    rnn_persist<<<NWG, 256, 0, stream>>>(x, Wih1, Whh1, bih1, bhh1,
                                         Wih2, Whh2, bih2, bhh2,
                                         Wlin, blin, (float*)d_out,
                                         (unsigned char*)d_ws);
}